// Round 1
// baseline (775.198 us; speedup 1.0000x reference)
//
#include <hip/hip_runtime.h>

#define N_NODES 50000
#define N_EDGES 640000
#define HID 128
#define EF 16
#define NLAYERS 3
#define CHUNK 32
#define SCAN_BLOCKS 196  // ceil(50000/256)

// Mt[l][k][j] = sum_i Wt[k,i] * We[l][i,j]   (16x128 per layer)
// ct[l][j]    = sum_i bt[i]  * We[l][i,j]
__global__ __launch_bounds__(256) void k_prep(const float* __restrict__ Wt,
                                              const float* __restrict__ bt,
                                              const float* __restrict__ We,
                                              float* __restrict__ Mt,
                                              float* __restrict__ ct) {
  int id = blockIdx.x * 256 + threadIdx.x;
  const int total = NLAYERS * (EF + 1) * HID;
  if (id >= total) return;
  int l = id / ((EF + 1) * HID);
  int r = id % ((EF + 1) * HID);
  int row = r / HID;
  int j = r % HID;
  const float* Wel = We + l * HID * HID;
  float s = 0.f;
  if (row < EF) {
    const float* wtr = Wt + row * HID;
    for (int i = 0; i < HID; ++i) s += wtr[i] * Wel[i * HID + j];
    Mt[(l * EF + row) * HID + j] = s;
  } else {
    for (int i = 0; i < HID; ++i) s += bt[i] * Wel[i * HID + j];
    ct[l * HID + j] = s;
  }
}

__global__ __launch_bounds__(256) void k_zero(int* __restrict__ counts, int* __restrict__ fill) {
  int id = blockIdx.x * 256 + threadIdx.x;
  if (id < N_NODES) { counts[id] = 0; fill[id] = 0; }
}

__global__ __launch_bounds__(256) void k_hist(const int* __restrict__ dst, int* __restrict__ counts) {
  int e = blockIdx.x * 256 + threadIdx.x;
  if (e < N_EDGES) atomicAdd(&counts[dst[e]], 1);
}

__global__ __launch_bounds__(256) void k_scan1(const int* __restrict__ counts,
                                               int* __restrict__ rowptr,
                                               int* __restrict__ bsum) {
  __shared__ int sc[256];
  int t = threadIdx.x;
  int i = blockIdx.x * 256 + t;
  int v = (i < N_NODES) ? counts[i] : 0;
  sc[t] = v;
  __syncthreads();
  for (int off = 1; off < 256; off <<= 1) {
    int u = 0;
    if (t >= off) u = sc[t - off];
    __syncthreads();
    sc[t] += u;
    __syncthreads();
  }
  if (i < N_NODES) rowptr[i] = sc[t] - v;  // block-local exclusive
  if (t == 255) bsum[blockIdx.x] = sc[255];
}

__global__ __launch_bounds__(256) void k_scan2(int* __restrict__ bsum) {
  __shared__ int sc[256];
  int t = threadIdx.x;
  int v = (t < SCAN_BLOCKS) ? bsum[t] : 0;
  sc[t] = v;
  __syncthreads();
  for (int off = 1; off < 256; off <<= 1) {
    int u = 0;
    if (t >= off) u = sc[t - off];
    __syncthreads();
    sc[t] += u;
    __syncthreads();
  }
  bsum[t] = sc[t] - v;  // exclusive block offsets
}

__global__ __launch_bounds__(256) void k_scan3(int* __restrict__ rowptr, const int* __restrict__ bsum) {
  int t = threadIdx.x;
  int i = blockIdx.x * 256 + t;
  if (i < N_NODES) rowptr[i] += bsum[blockIdx.x];
  if (i == 0) rowptr[N_NODES] = N_EDGES;
}

__global__ __launch_bounds__(256) void k_fill(const int* __restrict__ src,
                                              const int* __restrict__ dst,
                                              const int* __restrict__ rowptr,
                                              int* __restrict__ fill,
                                              int* __restrict__ ssrc,
                                              int* __restrict__ seid) {
  int e = blockIdx.x * 256 + threadIdx.x;
  if (e >= N_EDGES) return;
  int d = dst[e];
  int pos = atomicAdd(&fill[d], 1);
  int idx = rowptr[d] + pos;
  ssrc[idx] = src[e];
  seid[idx] = e;
}

// xl = x@Wl + bl, xr = x@Wr + br. 64 rows x 128 cols per block, per-thread 8x4x2.
__global__ __launch_bounds__(256) void k_gemm(const float* __restrict__ x,
                                              const float* __restrict__ Wl,
                                              const float* __restrict__ bl,
                                              const float* __restrict__ Wr,
                                              const float* __restrict__ br,
                                              float* __restrict__ xl,
                                              float* __restrict__ xr) {
  __shared__ float xs[16][64];   // [k][row] transposed -> broadcast reads
  __shared__ float wls[16][HID];
  __shared__ float wrs[16][HID];
  int t = threadIdx.x;
  int row0 = blockIdx.x * 64;
  int tx = t & 31;   // col group: j0 = tx*4
  int ty = t >> 5;   // row group: r0 = ty*8
  float accL[8][4], accR[8][4];
#pragma unroll
  for (int i = 0; i < 8; ++i)
#pragma unroll
    for (int q = 0; q < 4; ++q) { accL[i][q] = 0.f; accR[i][q] = 0.f; }
  int lr = t >> 2, lf = t & 3;
  for (int k0 = 0; k0 < HID; k0 += 16) {
    int grow = row0 + lr;
    float4 xv = make_float4(0.f, 0.f, 0.f, 0.f);
    if (grow < N_NODES) xv = *(const float4*)(x + grow * HID + k0 + lf * 4);
    xs[lf * 4 + 0][lr] = xv.x;
    xs[lf * 4 + 1][lr] = xv.y;
    xs[lf * 4 + 2][lr] = xv.z;
    xs[lf * 4 + 3][lr] = xv.w;
#pragma unroll
    for (int i = 0; i < 2; ++i) {
      int idx = t + i * 256;
      int kk = idx >> 5;
      int j4 = (idx & 31) * 4;
      *(float4*)(&wls[kk][j4]) = *(const float4*)(Wl + (k0 + kk) * HID + j4);
      *(float4*)(&wrs[kk][j4]) = *(const float4*)(Wr + (k0 + kk) * HID + j4);
    }
    __syncthreads();
#pragma unroll
    for (int kk = 0; kk < 16; ++kk) {
      float xv8[8];
#pragma unroll
      for (int i = 0; i < 8; ++i) xv8[i] = xs[kk][ty * 8 + i];
      float4 wl4 = *(float4*)(&wls[kk][tx * 4]);
      float4 wr4 = *(float4*)(&wrs[kk][tx * 4]);
#pragma unroll
      for (int i = 0; i < 8; ++i) {
        accL[i][0] += xv8[i] * wl4.x; accL[i][1] += xv8[i] * wl4.y;
        accL[i][2] += xv8[i] * wl4.z; accL[i][3] += xv8[i] * wl4.w;
        accR[i][0] += xv8[i] * wr4.x; accR[i][1] += xv8[i] * wr4.y;
        accR[i][2] += xv8[i] * wr4.z; accR[i][3] += xv8[i] * wr4.w;
      }
    }
    __syncthreads();
  }
  float4 blv = *(const float4*)(bl + tx * 4);
  float4 brv = *(const float4*)(br + tx * 4);
#pragma unroll
  for (int i = 0; i < 8; ++i) {
    int grow = row0 + ty * 8 + i;
    if (grow < N_NODES) {
      float4 o;
      o.x = accL[i][0] + blv.x; o.y = accL[i][1] + blv.y;
      o.z = accL[i][2] + blv.z; o.w = accL[i][3] + blv.w;
      *(float4*)(xl + grow * HID + tx * 4) = o;
      float4 p;
      p.x = accR[i][0] + brv.x; p.y = accR[i][1] + brv.y;
      p.z = accR[i][2] + brv.z; p.w = accR[i][3] + brv.w;
      *(float4*)(xr + grow * HID + tx * 4) = p;
    }
  }
}

// One block (128 threads) per destination node: edge loop (em + leaky + per-head
// logit via shfl + softmax-no-max + weighted aggregate), then bias + LN + ReLU + residual.
__global__ __launch_bounds__(128) void k_fused(const float* __restrict__ xin,
                                               const float* __restrict__ xl,
                                               const float* __restrict__ xr,
                                               const float* __restrict__ eattr,
                                               const int* __restrict__ rowptr,
                                               const int* __restrict__ ssrc,
                                               const int* __restrict__ seid,
                                               const float* __restrict__ Mt,
                                               const float* __restrict__ ct,
                                               const float* __restrict__ att,
                                               const float* __restrict__ bias_o,
                                               const float* __restrict__ lng,
                                               const float* __restrict__ lnb,
                                               float* __restrict__ xout) {
  __shared__ float ea_s[CHUNK][EF];
  __shared__ int src_s[CHUNK];
  __shared__ float red[4];
  int n = blockIdx.x;
  int j = threadIdx.x;  // channel 0..127; head = j/16
  float mt[EF];
#pragma unroll
  for (int k = 0; k < EF; ++k) mt[k] = Mt[k * HID + j];
  float base = xr[n * HID + j] + ct[j];
  float attj = att[j];
  int beg = rowptr[n], end = rowptr[n + 1];
  float acc = 0.f, denom = 0.f;
  for (int c0 = beg; c0 < end; c0 += CHUNK) {
    int cnt = min(CHUNK, end - c0);
    __syncthreads();
    if (j < cnt) src_s[j] = ssrc[c0 + j];
    if (j < cnt * 4) {
      int i = j >> 2, part = j & 3;
      int e = seid[c0 + i];
      *(float4*)(&ea_s[i][part * 4]) = *(const float4*)(eattr + e * EF + part * 4);
    }
    __syncthreads();
    for (int i = 0; i < cnt; ++i) {
      int s = src_s[i];
      float xls = xl[s * HID + j];
      float m = base + xls;
#pragma unroll
      for (int k = 0; k < EF; ++k) m += ea_s[i][k] * mt[k];
      m = (m > 0.f) ? m : 0.2f * m;
      float v = m * attj;
      v += __shfl_xor(v, 1);
      v += __shfl_xor(v, 2);
      v += __shfl_xor(v, 4);
      v += __shfl_xor(v, 8);
      float p = __expf(v);  // logits are small (|v| <~ 2): max-subtraction unneeded
      denom += p;
      acc += xls * p;
    }
  }
  float outj = acc / (denom + 1e-16f) + bias_o[j];
  // LayerNorm over the 128 channels (2 waves -> LDS combine)
  float s1 = outj, s2 = outj * outj;
#pragma unroll
  for (int mask = 1; mask <= 32; mask <<= 1) {
    s1 += __shfl_xor(s1, mask);
    s2 += __shfl_xor(s2, mask);
  }
  __syncthreads();
  if ((j & 63) == 0) { red[(j >> 6) * 2] = s1; red[(j >> 6) * 2 + 1] = s2; }
  __syncthreads();
  float tot = red[0] + red[2];
  float tot2 = red[1] + red[3];
  float mu = tot * (1.f / 128.f);
  float var = tot2 * (1.f / 128.f) - mu * mu;
  float y = lng[j] * (outj - mu) * rsqrtf(var + 1e-5f) + lnb[j];
  xout[n * HID + j] = fmaxf(y, 0.f) + xin[n * HID + j];
}

extern "C" void kernel_launch(void* const* d_in, const int* in_sizes, int n_in,
                              void* d_out, int out_size, void* d_ws, size_t ws_size,
                              hipStream_t stream) {
  const float* x0    = (const float*)d_in[0];
  const int*   eidx  = (const int*)d_in[2];
  const float* eattr = (const float*)d_in[3];
  const float* Wt    = (const float*)d_in[4];
  const float* bt    = (const float*)d_in[5];
  const float* Wl    = (const float*)d_in[6];
  const float* bl    = (const float*)d_in[7];
  const float* Wr    = (const float*)d_in[8];
  const float* br    = (const float*)d_in[9];
  const float* We    = (const float*)d_in[10];
  const float* att   = (const float*)d_in[11];
  const float* bo    = (const float*)d_in[12];
  const float* lng   = (const float*)d_in[13];
  const float* lnb   = (const float*)d_in[14];
  float* out = (float*)d_out;
  const int* src = eidx;
  const int* dst = eidx + N_EDGES;

  char* ws = (char*)d_ws;
  size_t off = 0;
  auto alloc = [&](size_t bytes) {
    char* p = ws + off;
    off += (bytes + 255) & ~(size_t)255;
    return p;
  };
  float* Mt   = (float*)alloc((size_t)NLAYERS * EF * HID * 4);
  float* ct   = (float*)alloc((size_t)NLAYERS * HID * 4);
  int* counts = (int*)alloc((size_t)N_NODES * 4);
  int* rowptr = (int*)alloc((size_t)(N_NODES + 1) * 4);
  int* bsum   = (int*)alloc(256 * 4);
  int* fill   = (int*)alloc((size_t)N_NODES * 4);
  int* ssrc   = (int*)alloc((size_t)N_EDGES * 4);
  int* seid   = (int*)alloc((size_t)N_EDGES * 4);
  float* xl   = (float*)alloc((size_t)N_NODES * HID * 4);
  float* xr   = (float*)alloc((size_t)N_NODES * HID * 4);
  float* xbuf = (float*)alloc((size_t)N_NODES * HID * 4);

  hipLaunchKernelGGL(k_prep, dim3(26), dim3(256), 0, stream, Wt, bt, We, Mt, ct);
  hipLaunchKernelGGL(k_zero, dim3(SCAN_BLOCKS), dim3(256), 0, stream, counts, fill);
  hipLaunchKernelGGL(k_hist, dim3((N_EDGES + 255) / 256), dim3(256), 0, stream, dst, counts);
  hipLaunchKernelGGL(k_scan1, dim3(SCAN_BLOCKS), dim3(256), 0, stream, counts, rowptr, bsum);
  hipLaunchKernelGGL(k_scan2, dim3(1), dim3(256), 0, stream, bsum);
  hipLaunchKernelGGL(k_scan3, dim3(SCAN_BLOCKS), dim3(256), 0, stream, rowptr, bsum);
  hipLaunchKernelGGL(k_fill, dim3((N_EDGES + 255) / 256), dim3(256), 0, stream,
                     src, dst, rowptr, fill, ssrc, seid);

  for (int l = 0; l < NLAYERS; ++l) {
    const float* xin = (l == 0) ? x0 : (const float*)xbuf;
    float* xout = (l == NLAYERS - 1) ? out : xbuf;
    hipLaunchKernelGGL(k_gemm, dim3((N_NODES + 63) / 64), dim3(256), 0, stream,
                       xin, Wl + (size_t)l * HID * HID, bl + l * HID,
                       Wr + (size_t)l * HID * HID, br + l * HID, xl, xr);
    hipLaunchKernelGGL(k_fused, dim3(N_NODES), dim3(128), 0, stream,
                       xin, xl, xr, eattr, rowptr, ssrc, seid,
                       Mt + (size_t)l * EF * HID, ct + l * HID, att + l * HID,
                       bo + l * HID, lng + l * HID, lnb + l * HID, xout);
  }
}

// Round 2
// 654.878 us; speedup vs baseline: 1.1837x; 1.1837x over previous
//
#include <hip/hip_runtime.h>

#define N_NODES 50000
#define N_EDGES 640000
#define HID 128
#define EF 16
#define NLAYERS 3
#define CHUNK 32
#define SCAN_BLOCKS 196  // ceil(50000/256)

typedef __attribute__((ext_vector_type(8))) short short8;
typedef __attribute__((ext_vector_type(4))) float f32x4;

__device__ __forceinline__ unsigned short f2bf(float f) {
  unsigned int u = __float_as_uint(f);
  u = u + 0x7FFFu + ((u >> 16) & 1u);  // RNE
  return (unsigned short)(u >> 16);
}

// 16-lane butterfly sum via DPP (no LDS pipe): xor1,xor2 via quad_perm,
// xor4 via row_half_mirror, xor8 via row_mirror (rows are 16 lanes on CDNA).
__device__ __forceinline__ float dpp_hadd16(float v) {
  int x;
  x = __builtin_amdgcn_update_dpp(0, __float_as_int(v), 0xB1, 0xF, 0xF, true);
  v += __int_as_float(x);
  x = __builtin_amdgcn_update_dpp(0, __float_as_int(v), 0x4E, 0xF, 0xF, true);
  v += __int_as_float(x);
  x = __builtin_amdgcn_update_dpp(0, __float_as_int(v), 0x141, 0xF, 0xF, true);
  v += __int_as_float(x);
  x = __builtin_amdgcn_update_dpp(0, __float_as_int(v), 0x140, 0xF, 0xF, true);
  v += __int_as_float(x);
  return v;
}

// Mt[l][k][j] = sum_i Wt[k,i] * We[l][i,j]   (16x128 per layer)
// ct[l][j]    = sum_i bt[i]  * We[l][i,j]
__global__ __launch_bounds__(256) void k_prep(const float* __restrict__ Wt,
                                              const float* __restrict__ bt,
                                              const float* __restrict__ We,
                                              float* __restrict__ Mt,
                                              float* __restrict__ ct) {
  int id = blockIdx.x * 256 + threadIdx.x;
  const int total = NLAYERS * (EF + 1) * HID;
  if (id >= total) return;
  int l = id / ((EF + 1) * HID);
  int r = id % ((EF + 1) * HID);
  int row = r / HID;
  int j = r % HID;
  const float* Wel = We + l * HID * HID;
  float s = 0.f;
  if (row < EF) {
    const float* wtr = Wt + row * HID;
    for (int i = 0; i < HID; ++i) s += wtr[i] * Wel[i * HID + j];
    Mt[(l * EF + row) * HID + j] = s;
  } else {
    for (int i = 0; i < HID; ++i) s += bt[i] * Wel[i * HID + j];
    ct[l * HID + j] = s;
  }
}

// x0 (fp32) -> bf16
__global__ __launch_bounds__(256) void k_cvtx(const float* __restrict__ x,
                                              unsigned short* __restrict__ xbf) {
  int id = blockIdx.x * 256 + threadIdx.x;  // one per 8 elements
  const int total = N_NODES * HID / 8;
  if (id >= total) return;
  const float4* p = (const float4*)(x + id * 8);
  float4 a = p[0], b = p[1];
  unsigned short o[8] = {f2bf(a.x), f2bf(a.y), f2bf(a.z), f2bf(a.w),
                         f2bf(b.x), f2bf(b.y), f2bf(b.z), f2bf(b.w)};
  *(uint4*)(xbf + id * 8) = *(uint4*)o;
}

// WT_bf[l][s][n][k] = bf16( W_s[l][k][n] ),  s=0 -> Wl, s=1 -> Wr
__global__ __launch_bounds__(256) void k_cvtw(const float* __restrict__ Wl,
                                              const float* __restrict__ Wr,
                                              unsigned short* __restrict__ WT) {
  int id = blockIdx.x * 256 + threadIdx.x;
  const int total = NLAYERS * 2 * HID * HID;
  if (id >= total) return;
  int k = id & (HID - 1);
  int n = (id >> 7) & (HID - 1);
  int s = (id >> 14) & 1;
  int l = id >> 15;
  const float* W = (s == 0 ? Wl : Wr) + (size_t)l * HID * HID;
  WT[id] = f2bf(W[k * HID + n]);
}

__global__ __launch_bounds__(256) void k_zero(int* __restrict__ counts, int* __restrict__ fill) {
  int id = blockIdx.x * 256 + threadIdx.x;
  if (id < N_NODES) { counts[id] = 0; fill[id] = 0; }
}

__global__ __launch_bounds__(256) void k_hist(const int* __restrict__ dst, int* __restrict__ counts) {
  int e = blockIdx.x * 256 + threadIdx.x;
  if (e < N_EDGES) atomicAdd(&counts[dst[e]], 1);
}

__global__ __launch_bounds__(256) void k_scan1(const int* __restrict__ counts,
                                               int* __restrict__ rowptr,
                                               int* __restrict__ bsum) {
  __shared__ int sc[256];
  int t = threadIdx.x;
  int i = blockIdx.x * 256 + t;
  int v = (i < N_NODES) ? counts[i] : 0;
  sc[t] = v;
  __syncthreads();
  for (int off = 1; off < 256; off <<= 1) {
    int u = 0;
    if (t >= off) u = sc[t - off];
    __syncthreads();
    sc[t] += u;
    __syncthreads();
  }
  if (i < N_NODES) rowptr[i] = sc[t] - v;  // block-local exclusive
  if (t == 255) bsum[blockIdx.x] = sc[255];
}

__global__ __launch_bounds__(256) void k_scan2(int* __restrict__ bsum) {
  __shared__ int sc[256];
  int t = threadIdx.x;
  int v = (t < SCAN_BLOCKS) ? bsum[t] : 0;
  sc[t] = v;
  __syncthreads();
  for (int off = 1; off < 256; off <<= 1) {
    int u = 0;
    if (t >= off) u = sc[t - off];
    __syncthreads();
    sc[t] += u;
    __syncthreads();
  }
  bsum[t] = sc[t] - v;  // exclusive block offsets
}

__global__ __launch_bounds__(256) void k_scan3(int* __restrict__ rowptr, const int* __restrict__ bsum) {
  int t = threadIdx.x;
  int i = blockIdx.x * 256 + t;
  if (i < N_NODES) rowptr[i] += bsum[blockIdx.x];
  if (i == 0) rowptr[N_NODES] = N_EDGES;
}

__global__ __launch_bounds__(256) void k_fill(const int* __restrict__ src,
                                              const int* __restrict__ dst,
                                              const int* __restrict__ rowptr,
                                              int* __restrict__ fill,
                                              int* __restrict__ ssrc,
                                              int* __restrict__ seid) {
  int e = blockIdx.x * 256 + threadIdx.x;
  if (e >= N_EDGES) return;
  int d = dst[e];
  int pos = atomicAdd(&fill[d], 1);
  int idx = rowptr[d] + pos;
  ssrc[idx] = src[e];
  seid[idx] = e;
}

// bf16 MFMA node GEMM: out_s = x @ W_s + b_s.  Block: 64 rows x 128 cols,
// blockIdx.y selects s (0 -> xl/Wl/bl, 1 -> xr/Wr/br). 256 thr = 4 waves,
// wave w covers n in [w*32, w*32+32). A rows padded to 136 shorts (272 B)
// so the 16-lanes-same-column a/b frag reads are only 2-way conflicted (free).
__global__ __launch_bounds__(256) void k_gemm_mfma(const unsigned short* __restrict__ xbf,
                                                   const unsigned short* __restrict__ WTl,  // layer base: [2][128][128]
                                                   const float* __restrict__ bl,
                                                   const float* __restrict__ br,
                                                   float* __restrict__ xl,
                                                   float* __restrict__ xr) {
  __shared__ short As[64 * 136];
  __shared__ short Bs[128 * 136];
  int t = threadIdx.x;
  int s = blockIdx.y;
  int row0 = blockIdx.x * 64;

  // stage A: 64 rows x 128 bf16, 16B chunks
  const uint4* gx = (const uint4*)xbf;
#pragma unroll
  for (int p = 0; p < 4; ++p) {
    int c = t + p * 256;
    int row = c >> 4, col16 = c & 15;
    int grow = row0 + row;
    if (grow >= N_NODES) grow = N_NODES - 1;
    uint4 v = gx[grow * 16 + col16];
    *(uint4*)(&As[row * 136 + col16 * 8]) = v;
  }
  // stage B: 128 rows (n) x 128 bf16 of WT[s]
  const uint4* gw = (const uint4*)WTl;
#pragma unroll
  for (int p = 0; p < 8; ++p) {
    int c = t + p * 256;
    int row = c >> 4, col16 = c & 15;
    uint4 v = gw[s * 2048 + row * 16 + col16];
    *(uint4*)(&Bs[row * 136 + col16 * 8]) = v;
  }
  __syncthreads();

  int lane = t & 63, w = t >> 6;
  int quad = lane >> 4, lm = lane & 15;
  f32x4 acc[4][2];
#pragma unroll
  for (int mf = 0; mf < 4; ++mf)
#pragma unroll
    for (int nf = 0; nf < 2; ++nf) acc[mf][nf] = (f32x4)(0.f);

#pragma unroll
  for (int ks = 0; ks < 4; ++ks) {
    short8 af[4], bf[2];
#pragma unroll
    for (int mf = 0; mf < 4; ++mf)
      af[mf] = *(short8*)(&As[(mf * 16 + lm) * 136 + ks * 32 + quad * 8]);
#pragma unroll
    for (int nf = 0; nf < 2; ++nf)
      bf[nf] = *(short8*)(&Bs[(w * 32 + nf * 16 + lm) * 136 + ks * 32 + quad * 8]);
#pragma unroll
    for (int mf = 0; mf < 4; ++mf)
#pragma unroll
      for (int nf = 0; nf < 2; ++nf)
        acc[mf][nf] = __builtin_amdgcn_mfma_f32_16x16x32_bf16(af[mf], bf[nf], acc[mf][nf], 0, 0, 0);
  }

  const float* bias = (s == 0) ? bl : br;
  float* out = (s == 0) ? xl : xr;
#pragma unroll
  for (int nf = 0; nf < 2; ++nf) {
    int n = w * 32 + nf * 16 + lm;
    float bv = bias[n];
#pragma unroll
    for (int mf = 0; mf < 4; ++mf) {
#pragma unroll
      for (int r = 0; r < 4; ++r) {
        int grow = row0 + mf * 16 + quad * 4 + r;
        if (grow < N_NODES) out[grow * HID + n] = acc[mf][nf][r] + bv;
      }
    }
  }
}

// One block (128 threads) per destination node: edge loop (em + leaky + per-head
// logit via DPP reduce + softmax-no-max + weighted aggregate), then bias + LN +
// ReLU + residual; also writes the bf16 copy for the next layer's GEMM.
__global__ __launch_bounds__(128) void k_fused(const float* __restrict__ xin,
                                               const float* __restrict__ xl,
                                               const float* __restrict__ xr,
                                               const float* __restrict__ eattr,
                                               const int* __restrict__ rowptr,
                                               const int* __restrict__ ssrc,
                                               const int* __restrict__ seid,
                                               const float* __restrict__ Mt,
                                               const float* __restrict__ ct,
                                               const float* __restrict__ att,
                                               const float* __restrict__ bias_o,
                                               const float* __restrict__ lng,
                                               const float* __restrict__ lnb,
                                               float* __restrict__ xout,
                                               unsigned short* __restrict__ xbf_out) {
  __shared__ float ea_s[CHUNK][EF];
  __shared__ int src_s[CHUNK];
  __shared__ float red[4];
  int n = blockIdx.x;
  int j = threadIdx.x;  // channel 0..127; head = j/16
  float mt[EF];
#pragma unroll
  for (int k = 0; k < EF; ++k) mt[k] = Mt[k * HID + j];
  float base = xr[n * HID + j] + ct[j];
  float attj = att[j];
  int beg = rowptr[n], end = rowptr[n + 1];
  float acc = 0.f, denom = 0.f;
  for (int c0 = beg; c0 < end; c0 += CHUNK) {
    int cnt = min(CHUNK, end - c0);
    __syncthreads();
    if (j < cnt) src_s[j] = ssrc[c0 + j];
    if (j < cnt * 4) {
      int i = j >> 2, part = j & 3;
      int e = seid[c0 + i];
      *(float4*)(&ea_s[i][part * 4]) = *(const float4*)(eattr + e * EF + part * 4);
    }
    __syncthreads();
    for (int i = 0; i < cnt; ++i) {
      int s = src_s[i];
      float xls = xl[s * HID + j];
      float m = base + xls;
#pragma unroll
      for (int k = 0; k < EF; ++k) m += ea_s[i][k] * mt[k];
      m = (m > 0.f) ? m : 0.2f * m;
      float v = dpp_hadd16(m * attj);  // per-head logit, all 16 lanes get it
      float p = __expf(v);  // logits are small (|v| <~ 2): max-subtraction unneeded
      denom += p;
      acc += xls * p;
    }
  }
  float outj = acc / (denom + 1e-16f) + bias_o[j];
  // LayerNorm over the 128 channels (2 waves -> LDS combine)
  float s1 = outj, s2 = outj * outj;
#pragma unroll
  for (int mask = 1; mask <= 32; mask <<= 1) {
    s1 += __shfl_xor(s1, mask);
    s2 += __shfl_xor(s2, mask);
  }
  __syncthreads();
  if ((j & 63) == 0) { red[(j >> 6) * 2] = s1; red[(j >> 6) * 2 + 1] = s2; }
  __syncthreads();
  float tot = red[0] + red[2];
  float tot2 = red[1] + red[3];
  float mu = tot * (1.f / 128.f);
  float var = tot2 * (1.f / 128.f) - mu * mu;
  float y = lng[j] * (outj - mu) * rsqrtf(var + 1e-5f) + lnb[j];
  float res = fmaxf(y, 0.f) + xin[n * HID + j];
  xout[n * HID + j] = res;
  xbf_out[n * HID + j] = f2bf(res);
}

extern "C" void kernel_launch(void* const* d_in, const int* in_sizes, int n_in,
                              void* d_out, int out_size, void* d_ws, size_t ws_size,
                              hipStream_t stream) {
  const float* x0    = (const float*)d_in[0];
  const int*   eidx  = (const int*)d_in[2];
  const float* eattr = (const float*)d_in[3];
  const float* Wt    = (const float*)d_in[4];
  const float* bt    = (const float*)d_in[5];
  const float* Wl    = (const float*)d_in[6];
  const float* bl    = (const float*)d_in[7];
  const float* Wr    = (const float*)d_in[8];
  const float* br    = (const float*)d_in[9];
  const float* We    = (const float*)d_in[10];
  const float* att   = (const float*)d_in[11];
  const float* bo    = (const float*)d_in[12];
  const float* lng   = (const float*)d_in[13];
  const float* lnb   = (const float*)d_in[14];
  float* out = (float*)d_out;
  const int* src = eidx;
  const int* dst = eidx + N_EDGES;

  char* ws = (char*)d_ws;
  size_t off = 0;
  auto alloc = [&](size_t bytes) {
    char* p = ws + off;
    off += (bytes + 255) & ~(size_t)255;
    return p;
  };
  float* Mt   = (float*)alloc((size_t)NLAYERS * EF * HID * 4);
  float* ct   = (float*)alloc((size_t)NLAYERS * HID * 4);
  int* counts = (int*)alloc((size_t)N_NODES * 4);
  int* rowptr = (int*)alloc((size_t)(N_NODES + 1) * 4);
  int* bsum   = (int*)alloc(256 * 4);
  int* fill   = (int*)alloc((size_t)N_NODES * 4);
  int* ssrc   = (int*)alloc((size_t)N_EDGES * 4);
  int* seid   = (int*)alloc((size_t)N_EDGES * 4);
  float* xl   = (float*)alloc((size_t)N_NODES * HID * 4);
  float* xr   = (float*)alloc((size_t)N_NODES * HID * 4);
  float* xbuf = (float*)alloc((size_t)N_NODES * HID * 4);
  unsigned short* xbf = (unsigned short*)alloc((size_t)N_NODES * HID * 2);
  unsigned short* WTb = (unsigned short*)alloc((size_t)NLAYERS * 2 * HID * HID * 2);

  hipLaunchKernelGGL(k_prep, dim3(26), dim3(256), 0, stream, Wt, bt, We, Mt, ct);
  hipLaunchKernelGGL(k_cvtx, dim3((N_NODES * HID / 8 + 255) / 256), dim3(256), 0, stream, x0, xbf);
  hipLaunchKernelGGL(k_cvtw, dim3((NLAYERS * 2 * HID * HID + 255) / 256), dim3(256), 0, stream, Wl, Wr, WTb);
  hipLaunchKernelGGL(k_zero, dim3(SCAN_BLOCKS), dim3(256), 0, stream, counts, fill);
  hipLaunchKernelGGL(k_hist, dim3((N_EDGES + 255) / 256), dim3(256), 0, stream, dst, counts);
  hipLaunchKernelGGL(k_scan1, dim3(SCAN_BLOCKS), dim3(256), 0, stream, counts, rowptr, bsum);
  hipLaunchKernelGGL(k_scan2, dim3(1), dim3(256), 0, stream, bsum);
  hipLaunchKernelGGL(k_scan3, dim3(SCAN_BLOCKS), dim3(256), 0, stream, rowptr, bsum);
  hipLaunchKernelGGL(k_fill, dim3((N_EDGES + 255) / 256), dim3(256), 0, stream,
                     src, dst, rowptr, fill, ssrc, seid);

  for (int l = 0; l < NLAYERS; ++l) {
    const float* xin = (l == 0) ? x0 : (const float*)xbuf;
    float* xout = (l == NLAYERS - 1) ? out : xbuf;
    hipLaunchKernelGGL(k_gemm_mfma, dim3((N_NODES + 63) / 64, 2), dim3(256), 0, stream,
                       xbf, WTb + (size_t)l * 2 * HID * HID, bl + l * HID, br + l * HID, xl, xr);
    hipLaunchKernelGGL(k_fused, dim3(N_NODES), dim3(128), 0, stream,
                       xin, xl, xr, eattr, rowptr, ssrc, seid,
                       Mt + (size_t)l * EF * HID, ct + l * HID, att + l * HID,
                       bo + l * HID, lng + l * HID, lnb + l * HID, xout, xbf);
  }
}

// Round 3
// 558.450 us; speedup vs baseline: 1.3881x; 1.1727x over previous
//
#include <hip/hip_runtime.h>

#define N_NODES 50000
#define N_EDGES 640000
#define HID 128
#define EF 16
#define NLAYERS 3
#define CHUNK 32
#define SCAN_BLOCKS 196  // ceil(50000/256)

typedef __attribute__((ext_vector_type(8))) short short8;
typedef __attribute__((ext_vector_type(4))) float f32x4;
typedef __attribute__((ext_vector_type(2))) float f32x2;

__device__ __forceinline__ unsigned short f2bf(float f) {
  unsigned int u = __float_as_uint(f);
  u = u + 0x7FFFu + ((u >> 16) & 1u);  // RNE
  return (unsigned short)(u >> 16);
}

// 16-lane butterfly sum via DPP (no LDS pipe): xor1,xor2 via quad_perm,
// xor4 via row_half_mirror, xor8 via row_mirror (rows are 16 lanes on CDNA).
__device__ __forceinline__ float dpp_hadd16(float v) {
  int x;
  x = __builtin_amdgcn_update_dpp(0, __float_as_int(v), 0xB1, 0xF, 0xF, true);
  v += __int_as_float(x);
  x = __builtin_amdgcn_update_dpp(0, __float_as_int(v), 0x4E, 0xF, 0xF, true);
  v += __int_as_float(x);
  x = __builtin_amdgcn_update_dpp(0, __float_as_int(v), 0x141, 0xF, 0xF, true);
  v += __int_as_float(x);
  x = __builtin_amdgcn_update_dpp(0, __float_as_int(v), 0x140, 0xF, 0xF, true);
  v += __int_as_float(x);
  return v;
}

// channel j -> paired slot: lane l=(j&63) holds channels l (lo) and l+64 (hi)
__device__ __forceinline__ int pslot(int j) { return (j & 63) * 2 + (j >> 6); }

// Mt[l][k][slot(j)] = sum_i Wt[k,i] * We[l][i,j]   (16x128 per layer, paired cols)
// ct[l][slot(j)]    = sum_i bt[i]  * We[l][i,j]
__global__ __launch_bounds__(256) void k_prep(const float* __restrict__ Wt,
                                              const float* __restrict__ bt,
                                              const float* __restrict__ We,
                                              float* __restrict__ Mt,
                                              float* __restrict__ ct) {
  int id = blockIdx.x * 256 + threadIdx.x;
  const int total = NLAYERS * (EF + 1) * HID;
  if (id >= total) return;
  int l = id / ((EF + 1) * HID);
  int r = id % ((EF + 1) * HID);
  int row = r / HID;
  int j = r % HID;
  const float* Wel = We + l * HID * HID;
  float s = 0.f;
  if (row < EF) {
    const float* wtr = Wt + row * HID;
    for (int i = 0; i < HID; ++i) s += wtr[i] * Wel[i * HID + j];
    Mt[(l * EF + row) * HID + pslot(j)] = s;
  } else {
    for (int i = 0; i < HID; ++i) s += bt[i] * Wel[i * HID + j];
    ct[l * HID + pslot(j)] = s;
  }
}

// x0 (fp32) -> bf16
__global__ __launch_bounds__(256) void k_cvtx(const float* __restrict__ x,
                                              unsigned short* __restrict__ xbf) {
  int id = blockIdx.x * 256 + threadIdx.x;  // one per 8 elements
  const int total = N_NODES * HID / 8;
  if (id >= total) return;
  const float4* p = (const float4*)(x + id * 8);
  float4 a = p[0], b = p[1];
  unsigned short o[8] = {f2bf(a.x), f2bf(a.y), f2bf(a.z), f2bf(a.w),
                         f2bf(b.x), f2bf(b.y), f2bf(b.z), f2bf(b.w)};
  *(uint4*)(xbf + id * 8) = *(uint4*)o;
}

// WT_bf[l][s][n][k] = bf16( W_s[l][k][n] ),  s=0 -> Wl, s=1 -> Wr
__global__ __launch_bounds__(256) void k_cvtw(const float* __restrict__ Wl,
                                              const float* __restrict__ Wr,
                                              unsigned short* __restrict__ WT) {
  int id = blockIdx.x * 256 + threadIdx.x;
  const int total = NLAYERS * 2 * HID * HID;
  if (id >= total) return;
  int k = id & (HID - 1);
  int n = (id >> 7) & (HID - 1);
  int s = (id >> 14) & 1;
  int l = id >> 15;
  const float* W = (s == 0 ? Wl : Wr) + (size_t)l * HID * HID;
  WT[id] = f2bf(W[k * HID + n]);
}

__global__ __launch_bounds__(256) void k_zero(int* __restrict__ counts, int* __restrict__ fill) {
  int id = blockIdx.x * 256 + threadIdx.x;
  if (id < N_NODES) { counts[id] = 0; fill[id] = 0; }
}

__global__ __launch_bounds__(256) void k_hist(const int* __restrict__ dst, int* __restrict__ counts) {
  int e = blockIdx.x * 256 + threadIdx.x;
  if (e < N_EDGES) atomicAdd(&counts[dst[e]], 1);
}

__global__ __launch_bounds__(256) void k_scan1(const int* __restrict__ counts,
                                               int* __restrict__ rowptr,
                                               int* __restrict__ bsum) {
  __shared__ int sc[256];
  int t = threadIdx.x;
  int i = blockIdx.x * 256 + t;
  int v = (i < N_NODES) ? counts[i] : 0;
  sc[t] = v;
  __syncthreads();
  for (int off = 1; off < 256; off <<= 1) {
    int u = 0;
    if (t >= off) u = sc[t - off];
    __syncthreads();
    sc[t] += u;
    __syncthreads();
  }
  if (i < N_NODES) rowptr[i] = sc[t] - v;  // block-local exclusive
  if (t == 255) bsum[blockIdx.x] = sc[255];
}

__global__ __launch_bounds__(256) void k_scan2(int* __restrict__ bsum) {
  __shared__ int sc[256];
  int t = threadIdx.x;
  int v = (t < SCAN_BLOCKS) ? bsum[t] : 0;
  sc[t] = v;
  __syncthreads();
  for (int off = 1; off < 256; off <<= 1) {
    int u = 0;
    if (t >= off) u = sc[t - off];
    __syncthreads();
    sc[t] += u;
    __syncthreads();
  }
  bsum[t] = sc[t] - v;  // exclusive block offsets
}

__global__ __launch_bounds__(256) void k_scan3(int* __restrict__ rowptr, const int* __restrict__ bsum) {
  int t = threadIdx.x;
  int i = blockIdx.x * 256 + t;
  if (i < N_NODES) rowptr[i] += bsum[blockIdx.x];
  if (i == 0) rowptr[N_NODES] = N_EDGES;
}

__global__ __launch_bounds__(256) void k_fill(const int* __restrict__ src,
                                              const int* __restrict__ dst,
                                              const int* __restrict__ rowptr,
                                              int* __restrict__ fill,
                                              int* __restrict__ ssrc,
                                              int* __restrict__ seid) {
  int e = blockIdx.x * 256 + threadIdx.x;
  if (e >= N_EDGES) return;
  int d = dst[e];
  int pos = atomicAdd(&fill[d], 1);
  int idx = rowptr[d] + pos;
  ssrc[idx] = src[e];
  seid[idx] = e;
}

// bf16 MFMA node GEMM: out_s = x @ W_s + b_s, written in channel-PAIRED layout.
// Block: 64 rows x 128 cols, blockIdx.y selects s (0 -> xl, 1 -> xr).
__global__ __launch_bounds__(256) void k_gemm_mfma(const unsigned short* __restrict__ xbf,
                                                   const unsigned short* __restrict__ WTl,  // layer base: [2][128][128]
                                                   const float* __restrict__ bl,
                                                   const float* __restrict__ br,
                                                   float* __restrict__ xl,
                                                   float* __restrict__ xr) {
  __shared__ short As[64 * 136];
  __shared__ short Bs[128 * 136];
  int t = threadIdx.x;
  int s = blockIdx.y;
  int row0 = blockIdx.x * 64;

  // stage A: 64 rows x 128 bf16, 16B chunks
  const uint4* gx = (const uint4*)xbf;
#pragma unroll
  for (int p = 0; p < 4; ++p) {
    int c = t + p * 256;
    int row = c >> 4, col16 = c & 15;
    int grow = row0 + row;
    if (grow >= N_NODES) grow = N_NODES - 1;
    uint4 v = gx[grow * 16 + col16];
    *(uint4*)(&As[row * 136 + col16 * 8]) = v;
  }
  // stage B: 128 rows (n) x 128 bf16 of WT[s]
  const uint4* gw = (const uint4*)WTl;
#pragma unroll
  for (int p = 0; p < 8; ++p) {
    int c = t + p * 256;
    int row = c >> 4, col16 = c & 15;
    uint4 v = gw[s * 2048 + row * 16 + col16];
    *(uint4*)(&Bs[row * 136 + col16 * 8]) = v;
  }
  __syncthreads();

  int lane = t & 63, w = t >> 6;
  int quad = lane >> 4, lm = lane & 15;
  f32x4 acc[4][2];
#pragma unroll
  for (int mf = 0; mf < 4; ++mf)
#pragma unroll
    for (int nf = 0; nf < 2; ++nf) acc[mf][nf] = (f32x4)(0.f);

#pragma unroll
  for (int ks = 0; ks < 4; ++ks) {
    short8 af[4], bf[2];
#pragma unroll
    for (int mf = 0; mf < 4; ++mf)
      af[mf] = *(short8*)(&As[(mf * 16 + lm) * 136 + ks * 32 + quad * 8]);
#pragma unroll
    for (int nf = 0; nf < 2; ++nf)
      bf[nf] = *(short8*)(&Bs[(w * 32 + nf * 16 + lm) * 136 + ks * 32 + quad * 8]);
#pragma unroll
    for (int mf = 0; mf < 4; ++mf)
#pragma unroll
      for (int nf = 0; nf < 2; ++nf)
        acc[mf][nf] = __builtin_amdgcn_mfma_f32_16x16x32_bf16(af[mf], bf[nf], acc[mf][nf], 0, 0, 0);
  }

  const float* bias = (s == 0) ? bl : br;
  float* out = (s == 0) ? xl : xr;
#pragma unroll
  for (int nf = 0; nf < 2; ++nf) {
    int n = w * 32 + nf * 16 + lm;
    float bv = bias[n];
    int slot = pslot(n);
#pragma unroll
    for (int mf = 0; mf < 4; ++mf) {
#pragma unroll
      for (int r = 0; r < 4; ++r) {
        int grow = row0 + mf * 16 + quad * 4 + r;
        if (grow < N_NODES) out[grow * HID + slot] = acc[mf][nf][r] + bv;
      }
    }
  }
}

// ONE WAVE (64 threads) per destination node; lane l owns channels (l, l+64)
// via the paired layout. Packed fp32 (v_pk_*) for all per-channel math.
// Single-wave block -> s_barrier elided, no LDS reduce in the LN epilogue.
__global__ __launch_bounds__(64) void k_fused(const float* __restrict__ xin,
                                              const float* __restrict__ xl,   // paired
                                              const float* __restrict__ xr,   // paired
                                              const float* __restrict__ eattr,
                                              const int* __restrict__ rowptr,
                                              const int* __restrict__ ssrc,
                                              const int* __restrict__ seid,
                                              const float* __restrict__ Mt,   // paired cols
                                              const float* __restrict__ ct,   // paired
                                              const float* __restrict__ att,
                                              const float* __restrict__ bias_o,
                                              const float* __restrict__ lng,
                                              const float* __restrict__ lnb,
                                              float* __restrict__ xout,
                                              unsigned short* __restrict__ xbf_out) {
  __shared__ float ea_s[CHUNK][EF];
  __shared__ int src_s[CHUNK];
  int n = blockIdx.x;
  int l = threadIdx.x;  // lane 0..63; head lo = l/16, head hi = 4 + l/16
  f32x2 mtp[EF];
#pragma unroll
  for (int k = 0; k < EF; ++k) mtp[k] = *(const f32x2*)(&Mt[k * HID + l * 2]);
  f32x2 base = *(const f32x2*)(&xr[(size_t)n * HID + l * 2]) +
               *(const f32x2*)(&ct[l * 2]);
  f32x2 attp = {att[l], att[l + 64]};
  int beg = rowptr[n], end = rowptr[n + 1];
  f32x2 acc = {0.f, 0.f}, denom = {0.f, 0.f};
  for (int c0 = beg; c0 < end; c0 += CHUNK) {
    int cnt = min(CHUNK, end - c0);
    __syncthreads();
    if (l < cnt) src_s[l] = ssrc[c0 + l];
    for (int q = l; q < cnt * 4; q += 64) {
      int i = q >> 2, part = q & 3;
      int e = seid[c0 + i];
      *(float4*)(&ea_s[i][part * 4]) = *(const float4*)(eattr + e * EF + part * 4);
    }
    __syncthreads();
    for (int i = 0; i < cnt; ++i) {
      int s = src_s[i];
      f32x2 xls = *(const f32x2*)(xl + (size_t)s * HID + l * 2);
      f32x2 m = base + xls;
#pragma unroll
      for (int k = 0; k < EF; ++k) m += ea_s[i][k] * mtp[k];
      // leaky_relu(m, 0.2) = 0.6*m + 0.4*|m|  (branchless, packed)
      f32x2 am = {__int_as_float(__float_as_int(m.x) & 0x7FFFFFFF),
                  __int_as_float(__float_as_int(m.y) & 0x7FFFFFFF)};
      m = 0.6f * m + 0.4f * am;
      f32x2 v = m * attp;
      float plo = __expf(dpp_hadd16(v.x));  // logits small: no max-subtract
      float phi = __expf(dpp_hadd16(v.y));
      f32x2 p = {plo, phi};
      denom += p;
      acc += xls * p;
    }
  }
  f32x2 outp;
  outp.x = acc.x / (denom.x + 1e-16f) + bias_o[l];
  outp.y = acc.y / (denom.y + 1e-16f) + bias_o[l + 64];
  // LayerNorm over 128 channels: pair-sum then 64-lane butterfly (single wave)
  float s1 = outp.x + outp.y;
  float s2 = outp.x * outp.x + outp.y * outp.y;
#pragma unroll
  for (int mask = 1; mask <= 32; mask <<= 1) {
    s1 += __shfl_xor(s1, mask);
    s2 += __shfl_xor(s2, mask);
  }
  float mu = s1 * (1.f / 128.f);
  float var = s2 * (1.f / 128.f) - mu * mu;
  float rs = rsqrtf(var + 1e-5f);
  float y0 = lng[l] * (outp.x - mu) * rs + lnb[l];
  float y1 = lng[l + 64] * (outp.y - mu) * rs + lnb[l + 64];
  float r0 = fmaxf(y0, 0.f) + xin[(size_t)n * HID + l];
  float r1 = fmaxf(y1, 0.f) + xin[(size_t)n * HID + l + 64];
  xout[(size_t)n * HID + l] = r0;
  xout[(size_t)n * HID + l + 64] = r1;
  xbf_out[(size_t)n * HID + l] = f2bf(r0);
  xbf_out[(size_t)n * HID + l + 64] = f2bf(r1);
}

extern "C" void kernel_launch(void* const* d_in, const int* in_sizes, int n_in,
                              void* d_out, int out_size, void* d_ws, size_t ws_size,
                              hipStream_t stream) {
  const float* x0    = (const float*)d_in[0];
  const int*   eidx  = (const int*)d_in[2];
  const float* eattr = (const float*)d_in[3];
  const float* Wt    = (const float*)d_in[4];
  const float* bt    = (const float*)d_in[5];
  const float* Wl    = (const float*)d_in[6];
  const float* bl    = (const float*)d_in[7];
  const float* Wr    = (const float*)d_in[8];
  const float* br    = (const float*)d_in[9];
  const float* We    = (const float*)d_in[10];
  const float* att   = (const float*)d_in[11];
  const float* bo    = (const float*)d_in[12];
  const float* lng   = (const float*)d_in[13];
  const float* lnb   = (const float*)d_in[14];
  float* out = (float*)d_out;
  const int* src = eidx;
  const int* dst = eidx + N_EDGES;

  char* ws = (char*)d_ws;
  size_t off = 0;
  auto alloc = [&](size_t bytes) {
    char* p = ws + off;
    off += (bytes + 255) & ~(size_t)255;
    return p;
  };
  float* Mt   = (float*)alloc((size_t)NLAYERS * EF * HID * 4);
  float* ct   = (float*)alloc((size_t)NLAYERS * HID * 4);
  int* counts = (int*)alloc((size_t)N_NODES * 4);
  int* rowptr = (int*)alloc((size_t)(N_NODES + 1) * 4);
  int* bsum   = (int*)alloc(256 * 4);
  int* fill   = (int*)alloc((size_t)N_NODES * 4);
  int* ssrc   = (int*)alloc((size_t)N_EDGES * 4);
  int* seid   = (int*)alloc((size_t)N_EDGES * 4);
  float* xl   = (float*)alloc((size_t)N_NODES * HID * 4);
  float* xr   = (float*)alloc((size_t)N_NODES * HID * 4);
  float* xbuf = (float*)alloc((size_t)N_NODES * HID * 4);
  unsigned short* xbf = (unsigned short*)alloc((size_t)N_NODES * HID * 2);
  unsigned short* WTb = (unsigned short*)alloc((size_t)NLAYERS * 2 * HID * HID * 2);

  hipLaunchKernelGGL(k_prep, dim3(26), dim3(256), 0, stream, Wt, bt, We, Mt, ct);
  hipLaunchKernelGGL(k_cvtx, dim3((N_NODES * HID / 8 + 255) / 256), dim3(256), 0, stream, x0, xbf);
  hipLaunchKernelGGL(k_cvtw, dim3((NLAYERS * 2 * HID * HID + 255) / 256), dim3(256), 0, stream, Wl, Wr, WTb);
  hipLaunchKernelGGL(k_zero, dim3(SCAN_BLOCKS), dim3(256), 0, stream, counts, fill);
  hipLaunchKernelGGL(k_hist, dim3((N_EDGES + 255) / 256), dim3(256), 0, stream, dst, counts);
  hipLaunchKernelGGL(k_scan1, dim3(SCAN_BLOCKS), dim3(256), 0, stream, counts, rowptr, bsum);
  hipLaunchKernelGGL(k_scan2, dim3(1), dim3(256), 0, stream, bsum);
  hipLaunchKernelGGL(k_scan3, dim3(SCAN_BLOCKS), dim3(256), 0, stream, rowptr, bsum);
  hipLaunchKernelGGL(k_fill, dim3((N_EDGES + 255) / 256), dim3(256), 0, stream,
                     src, dst, rowptr, fill, ssrc, seid);

  for (int l = 0; l < NLAYERS; ++l) {
    const float* xin = (l == 0) ? x0 : (const float*)xbuf;
    float* xout = (l == NLAYERS - 1) ? out : xbuf;
    hipLaunchKernelGGL(k_gemm_mfma, dim3((N_NODES + 63) / 64, 2), dim3(256), 0, stream,
                       xbf, WTb + (size_t)l * 2 * HID * HID, bl + l * HID, br + l * HID, xl, xr);
    hipLaunchKernelGGL(k_fused, dim3(N_NODES), dim3(64), 0, stream,
                       xin, xl, xr, eattr, rowptr, ssrc, seid,
                       Mt + (size_t)l * EF * HID, ct + l * HID, att + l * HID,
                       bo + l * HID, lng + l * HID, lnb + l * HID, xout, xbf);
  }
}